// Round 4
// baseline (287.144 us; speedup 1.0000x reference)
//
#include <hip/hip_runtime.h>
#include <stdint.h>

typedef unsigned short u16;
typedef __attribute__((ext_vector_type(8))) short bf16x8;
typedef __attribute__((ext_vector_type(4))) short s16x4;
typedef __attribute__((ext_vector_type(4))) float f32x4;

#define MFMA16(a,b,c) __builtin_amdgcn_mfma_f32_16x16x32_bf16((a),(b),(c),0,0,0)

__device__ __forceinline__ u16 f2bf(float f) {
  union { float f; uint32_t u; } v; v.f = f;
  return (u16)((v.u + 0x7fffu + ((v.u >> 16) & 1u)) >> 16);
}

// async 16B global->LDS (lds dest = wave-uniform base + lane*16)
__device__ __forceinline__ void gload16(const void* g, void* l) {
  __builtin_amdgcn_global_load_lds((const __attribute__((address_space(1))) void*)g,
                                   (__attribute__((address_space(3))) void*)l, 16, 0, 0);
}

// Stage a 128x64 bf16 tile into lds[128*64] with chunk-xor swizzle.
// Physical chunk (r, pc) holds logical chunk (r, pc^(r&7)).
__device__ __forceinline__ void stage256(const u16* src, size_t stride, u16* lds, int tid) {
#pragma unroll
  for (int i = 0; i < 4; ++i) {
    const int L = i * 256 + tid;       // chunk 0..1023
    const int r = L >> 3, pc = L & 7;
    const int lc = pc ^ (r & 7);
    gload16(src + (size_t)r * stride + lc * 8, lds + (size_t)(i * 256 + (tid & ~63)) * 8);
  }
}
// read logical chunk kc of row from a swizzled (rows x 64) tile
#define TILE_AT(lds, row, kc) \
  (*(const bf16x8*)&(lds)[((((row) << 3) + ((kc) ^ ((row) & 7)))) << 3])

// ---------- kernel 1: cast hidden_states fp32 -> bf16 ----------
__global__ void k_cast(const float* __restrict__ src, u16* __restrict__ dst, int n8) {
  int idx = blockIdx.x * 256 + threadIdx.x;
  if (idx >= n8) return;
  const float4* s = (const float4*)src + (size_t)idx * 2;
  float4 a = s[0], b = s[1];
  bf16x8 o;
  o[0] = (short)f2bf(a.x); o[1] = (short)f2bf(a.y);
  o[2] = (short)f2bf(a.z); o[3] = (short)f2bf(a.w);
  o[4] = (short)f2bf(b.x); o[5] = (short)f2bf(b.y);
  o[6] = (short)f2bf(b.z); o[7] = (short)f2bf(b.w);
  *(bf16x8*)(dst + (size_t)idx * 8) = o;
}

// ---------- kernel 2: transpose+cast weight: Wt[j][d] = bf16(W[d][j]) ----------
__global__ void k_wtrans(const float* __restrict__ W, u16* __restrict__ Wt) {
  __shared__ u16 tile[32][33];
  int bd = blockIdx.x >> 5, bj = blockIdx.x & 31;
  int tx = threadIdx.x & 31, ty = threadIdx.x >> 5;
#pragma unroll
  for (int i = 0; i < 32; i += 8)
    tile[ty + i][tx] = f2bf(W[(size_t)(bd * 32 + ty + i) * 1024 + bj * 32 + tx]);
  __syncthreads();
#pragma unroll
  for (int i = 0; i < 32; i += 8)
    Wt[(size_t)(bj * 32 + ty + i) * 1024 + bd * 32 + tx] = tile[tx][ty + i];
}

// ---------- kernel 3: zero output ----------
__global__ void k_zero(float4* __restrict__ p, int n4) {
  int idx = blockIdx.x * 256 + threadIdx.x;
  if (idx < n4) p[idx] = make_float4(0.f, 0.f, 0.f, 0.f);
}

// ---------- kernel 4: fused QKV GEMM, counted-wait double buffer ----------
__global__ __launch_bounds__(256, 2) void k_qkv(
    const u16* __restrict__ hsb, const u16* __restrict__ Wt,
    const float* __restrict__ bq, const float* __restrict__ bk, const float* __restrict__ bv,
    u16* __restrict__ Qb, u16* __restrict__ Kb, u16* __restrict__ Vt) {
  __shared__ u16 a_lds[2][128 * 64];
  __shared__ u16 b_lds[2][128 * 64];
  const int tid = threadIdx.x;
  const int lane = tid & 63, wid = tid >> 6;
  const int l15 = lane & 15, quad = lane >> 4;
  const int wr = wid >> 1, wc = wid & 1;
  const int bx = blockIdx.x & 31;
  const int by = blockIdx.x >> 5;
  const int Mbase = bx * 128;
  const int widx = by >> 3;               // 0=Q 1=K 2=V
  const int Nloc = (by & 7) * 128;

  f32x4 acc[4][4];
#pragma unroll
  for (int i = 0; i < 4; ++i)
#pragma unroll
    for (int j = 0; j < 4; ++j) acc[i][j] = (f32x4){0.f, 0.f, 0.f, 0.f};

  const u16* asrc = hsb + (size_t)Mbase * 1024;
  const u16* bsrc = Wt + (size_t)widx * 1048576 + (size_t)Nloc * 1024;

  stage256(asrc, 1024, a_lds[0], tid);
  stage256(bsrc, 1024, b_lds[0], tid);

  for (int kb = 0; kb < 16; ++kb) {
    const int cur = kb & 1;
    asm volatile("s_waitcnt vmcnt(0)" ::: "memory");
    __builtin_amdgcn_s_barrier();
    asm volatile("" ::: "memory");
    if (kb < 15) {
      stage256(asrc + (kb + 1) * 64, 1024, a_lds[cur ^ 1], tid);
      stage256(bsrc + (kb + 1) * 64, 1024, b_lds[cur ^ 1], tid);
    }
#pragma unroll
    for (int ks = 0; ks < 2; ++ks) {
      const int kc = ks * 4 + quad;
      bf16x8 af[4], bfr[4];
#pragma unroll
      for (int mt = 0; mt < 4; ++mt) af[mt] = TILE_AT(a_lds[cur], wr * 64 + mt * 16 + l15, kc);
#pragma unroll
      for (int nt = 0; nt < 4; ++nt) bfr[nt] = TILE_AT(b_lds[cur], wc * 64 + nt * 16 + l15, kc);
#pragma unroll
      for (int mt = 0; mt < 4; ++mt)
#pragma unroll
        for (int nt = 0; nt < 4; ++nt)
          acc[mt][nt] = MFMA16(af[mt], bfr[nt], acc[mt][nt]);
    }
  }
  const float* bias = (widx == 0) ? bq : ((widx == 1) ? bk : bv);
#pragma unroll
  for (int nt = 0; nt < 4; ++nt) {
    const int jloc = Nloc + wc * 64 + nt * 16 + l15;
    const float bias_v = bias[jloc];
#pragma unroll
    for (int mt = 0; mt < 4; ++mt) {
      const int Mr0 = Mbase + wr * 64 + mt * 16 + quad * 4;
      if (widx == 2) {
        const int b = Mr0 >> 11, mseq = Mr0 & 2047;
        const int g = jloc >> 7, h = jloc & 127;
        s16x4 pk;
#pragma unroll
        for (int r = 0; r < 4; ++r) pk[r] = (short)f2bf(acc[mt][nt][r] + bias_v);
        *(s16x4*)(Vt + (((size_t)b * 8 + g) * 128 + h) * 2048 + mseq) = pk;
      } else {
        u16* dst = (widx == 0) ? Qb : Kb;
#pragma unroll
        for (int r = 0; r < 4; ++r)
          dst[(size_t)(Mr0 + r) * 1024 + jloc] = f2bf(acc[mt][nt][r] + bias_v);
      }
    }
  }
}

// ---------- kernel 5: FUSED scores + softmax-over-g + PV ----------
// grid 256 = 64 nt x {b,msub}; bx = nt*4 + (b*2+msub) so XCD = bx&7 maps each
// XCD to ONE (b,msub) combo (512 KB K/V chunk working set hot in its L2).
// Block: 512 thr = 8 waves; stage Q[32n x 1024h] (64 KB LDS) once; loop 8
// m-chunks of 128:
//   QK^T: wave w owns m-rows w*16..+16, all 8 g; softmax over g register-local
//   pack P -> p_lds[8g][32n][128m] bf16 (64 KB, chunk-xor swizzled by n&7)
//   PV: wave g=w contracts P[g] (A-operand, n rows) x Vt[g] (B-operand, h rows)
//       into persistent acc[2 nf][8 hf] (64 regs), V streamed from L2.
// Out: f32 atomicAdd (2 msub contributions per element, out pre-zeroed).
__global__ __launch_bounds__(512, 2) void k_att(
    const u16* __restrict__ Qb, const u16* __restrict__ Kb,
    const u16* __restrict__ Vt, float* __restrict__ out) {
  __shared__ u16 q_lds[32 * 1024];    // 64 KB
  __shared__ u16 p_lds[8 * 32 * 128]; // 64 KB
  const int tid = threadIdx.x;
  const int w = tid >> 6;             // wave id; also PV's g
  const int lane = tid & 63;
  const int l15 = lane & 15, quad = lane >> 4;
  const int bx = blockIdx.x;
  const int nt = bx >> 2;
  const int bcoord = (bx >> 1) & 1;
  const int msub = bx & 1;
  const int nbase = nt * 32;
  const size_t boff = (size_t)bcoord * 2048;

  // stage Q tile 32 x 1024 (4096 16B-chunks, 8 per thread), swizzled source
#pragma unroll
  for (int i = 0; i < 8; ++i) {
    const int idx = i * 512 + tid;
    const int r = idx >> 7, pc = idx & 127;
    const int lc = pc ^ (r & 7);
    gload16(Qb + (boff + nbase + r) * 1024 + lc * 8,
            q_lds + (size_t)(i * 512 + (tid & ~63)) * 8);
  }

  f32x4 acc[2][8];
#pragma unroll
  for (int nf = 0; nf < 2; ++nf)
#pragma unroll
    for (int hf = 0; hf < 8; ++hf) acc[nf][hf] = (f32x4){0.f, 0.f, 0.f, 0.f};

  const u16* vbase = Vt + ((size_t)(bcoord * 8 + w) * 128) * 2048;
  const int lc_w = w * 2 + (quad >> 1);      // logical m-chunk of this lane's P
  const int sub = (quad & 1) * 4;            // u16 offset within chunk

  __syncthreads();

  for (int mc = 0; mc < 8; ++mc) {
    const int m0 = msub * 1024 + mc * 128;
    const u16* kp = Kb + (boff + m0 + w * 16 + l15) * 1024 + quad * 8;

    f32x4 sacc[2][8];
#pragma unroll
    for (int nf = 0; nf < 2; ++nf)
#pragma unroll
      for (int g = 0; g < 8; ++g) sacc[nf][g] = (f32x4){0.f, 0.f, 0.f, 0.f};

    // 2-deep K-fragment ring
    bf16x8 kf[2][4];
#pragma unroll
    for (int ks = 0; ks < 4; ++ks) kf[0][ks] = *(const bf16x8*)(kp + ks * 32);
#pragma unroll
    for (int g = 0; g < 8; ++g) {
      if (g < 7) {
#pragma unroll
        for (int ks = 0; ks < 4; ++ks)
          kf[(g + 1) & 1][ks] = *(const bf16x8*)(kp + (g + 1) * 128 + ks * 32);
      }
      __builtin_amdgcn_s_setprio(1);
#pragma unroll
      for (int ks = 0; ks < 4; ++ks) {
        const int kc = g * 16 + ks * 4 + quad;   // logical h-chunk
#pragma unroll
        for (int nf = 0; nf < 2; ++nf) {
          const int row = nf * 16 + l15;
          bf16x8 qf = *(const bf16x8*)&q_lds[row * 1024 + ((kc ^ (row & 7)) << 3)];
          sacc[nf][g] = MFMA16(kf[g & 1][ks], qf, sacc[nf][g]);  // D[m][n]
        }
      }
      __builtin_amdgcn_s_setprio(0);
    }
    // softmax over g (register-local): lane holds n=l15(+16nf), m=w*16+quad*4+r
#pragma unroll
    for (int nf = 0; nf < 2; ++nf)
#pragma unroll
      for (int r = 0; r < 4; ++r) {
        float s[8];
#pragma unroll
        for (int g = 0; g < 8; ++g) s[g] = sacc[nf][g][r] * 0.03125f;
        float mx = s[0];
#pragma unroll
        for (int g = 1; g < 8; ++g) mx = fmaxf(mx, s[g]);
        float sum = 0.f;
#pragma unroll
        for (int g = 0; g < 8; ++g) { s[g] = __expf(s[g] - mx); sum += s[g]; }
        const float rs = 1.0f / sum;
#pragma unroll
        for (int g = 0; g < 8; ++g) sacc[nf][g][r] = s[g] * rs;
      }
    // pack P -> p_lds[g][n][m], 4 consecutive m per lane -> b64 writes
#pragma unroll
    for (int g = 0; g < 8; ++g)
#pragma unroll
      for (int nf = 0; nf < 2; ++nf) {
        const int n = nf * 16 + l15;
        s16x4 pk;
#pragma unroll
        for (int r = 0; r < 4; ++r) pk[r] = (short)f2bf(sacc[nf][g][r]);
        *(s16x4*)&p_lds[(size_t)((g * 32 + n) << 7) + ((lc_w ^ (n & 7)) << 3) + sub] = pk;
      }
    __syncthreads();
    // PV: wave owns g = w. D[n][h] = P[n][m] * V[h][m]^T
#pragma unroll
    for (int kblk = 0; kblk < 4; ++kblk) {
      bf16x8 pf[2];
#pragma unroll
      for (int nf = 0; nf < 2; ++nf) {
        const int n = nf * 16 + l15;
        pf[nf] = *(const bf16x8*)&p_lds[(size_t)((w * 32 + n) << 7) +
                                        (((kblk * 4 + quad) ^ (n & 7)) << 3)];
      }
      __builtin_amdgcn_s_setprio(1);
#pragma unroll
      for (int hf = 0; hf < 8; ++hf) {
        bf16x8 vf = *(const bf16x8*)(vbase + (size_t)(hf * 16 + l15) * 2048 +
                                     m0 + kblk * 32 + quad * 8);
#pragma unroll
        for (int nf = 0; nf < 2; ++nf)
          acc[nf][hf] = MFMA16(pf[nf], vf, acc[nf][hf]);
      }
      __builtin_amdgcn_s_setprio(0);
    }
    __syncthreads();
  }
  // accumulate into out: row n = nbase + nf*16 + quad*4 + r, col = g*128 + hf*16 + l15
#pragma unroll
  for (int nf = 0; nf < 2; ++nf)
#pragma unroll
    for (int hf = 0; hf < 8; ++hf) {
      const int col = w * 128 + hf * 16 + l15;
#pragma unroll
      for (int r = 0; r < 4; ++r) {
        const int nrow = nbase + nf * 16 + quad * 4 + r;
        atomicAdd(out + (boff + nrow) * 1024 + col, acc[nf][hf][r]);
      }
    }
}

extern "C" void kernel_launch(void* const* d_in, const int* in_sizes, int n_in,
                              void* d_out, int out_size, void* d_ws, size_t ws_size,
                              hipStream_t stream) {
  const float* hs = (const float*)d_in[0];
  const float* Wq = (const float*)d_in[1];
  const float* bq = (const float*)d_in[2];
  const float* Wk = (const float*)d_in[3];
  const float* bk = (const float*)d_in[4];
  const float* Wv = (const float*)d_in[5];
  const float* bv = (const float*)d_in[6];
  float* out = (float*)d_out;

  u16* ws = (u16*)d_ws;
  u16* hsb = ws;                   // 4096x1024
  u16* Wt  = ws + 4194304;         // 3 x 1024x1024 (j-major)
  u16* Qb  = ws + 7340032;         // [b][n][1024]
  u16* Kb  = ws + 11534336;        // [b][m][1024]
  u16* Vt  = ws + 15728640;        // [b][g][h][m] = [2][8][128][2048]

  k_cast<<<2048, 256, 0, stream>>>(hs, hsb, 524288);
  k_wtrans<<<1024, 256, 0, stream>>>(Wq, Wt);
  k_wtrans<<<1024, 256, 0, stream>>>(Wk, Wt + 1048576);
  k_wtrans<<<1024, 256, 0, stream>>>(Wv, Wt + 2097152);
  k_qkv<<<32 * 24, 256, 0, stream>>>(hsb, Wt, bq, bk, bv, Qb, Kb, Vt);
  k_zero<<<4096, 256, 0, stream>>>((float4*)out, 1048576);
  k_att<<<256, 512, 0, stream>>>(Qb, Kb, Vt, out);
}

// Round 5
// 284.946 us; speedup vs baseline: 1.0077x; 1.0077x over previous
//
#include <hip/hip_runtime.h>
#include <stdint.h>

typedef unsigned short u16;
typedef __attribute__((ext_vector_type(8))) short bf16x8;
typedef __attribute__((ext_vector_type(4))) short s16x4;
typedef __attribute__((ext_vector_type(4))) float f32x4;

#define MFMA16(a,b,c) __builtin_amdgcn_mfma_f32_16x16x32_bf16((a),(b),(c),0,0,0)

__device__ __forceinline__ u16 f2bf(float f) {
  union { float f; uint32_t u; } v; v.f = f;
  return (u16)((v.u + 0x7fffu + ((v.u >> 16) & 1u)) >> 16);
}

// async 16B global->LDS (lds dest = wave-uniform base + lane*16)
__device__ __forceinline__ void gload16(const void* g, void* l) {
  __builtin_amdgcn_global_load_lds((const __attribute__((address_space(1))) void*)g,
                                   (__attribute__((address_space(3))) void*)l, 16, 0, 0);
}

// Stage a 128x64 bf16 tile into lds[128*64] with chunk-xor swizzle.
// Physical chunk (r, pc) holds logical chunk (r, pc^(r&7)).
__device__ __forceinline__ void stage256(const u16* src, size_t stride, u16* lds, int tid) {
#pragma unroll
  for (int i = 0; i < 4; ++i) {
    const int L = i * 256 + tid;       // chunk 0..1023
    const int r = L >> 3, pc = L & 7;
    const int lc = pc ^ (r & 7);
    gload16(src + (size_t)r * stride + lc * 8, lds + (size_t)(i * 256 + (tid & ~63)) * 8);
  }
}
// read logical chunk kc of row from a swizzled (rows x 64) tile
#define TILE_AT(lds, row, kc) \
  (*(const bf16x8*)&(lds)[((((row) << 3) + ((kc) ^ ((row) & 7)))) << 3])

// ---------- kernel 1: cast hidden_states fp32 -> bf16 ----------
__global__ void k_cast(const float* __restrict__ src, u16* __restrict__ dst, int n8) {
  int idx = blockIdx.x * 256 + threadIdx.x;
  if (idx >= n8) return;
  const float4* s = (const float4*)src + (size_t)idx * 2;
  float4 a = s[0], b = s[1];
  bf16x8 o;
  o[0] = (short)f2bf(a.x); o[1] = (short)f2bf(a.y);
  o[2] = (short)f2bf(a.z); o[3] = (short)f2bf(a.w);
  o[4] = (short)f2bf(b.x); o[5] = (short)f2bf(b.y);
  o[6] = (short)f2bf(b.z); o[7] = (short)f2bf(b.w);
  *(bf16x8*)(dst + (size_t)idx * 8) = o;
}

// ---------- kernel 2: transpose+cast weight: Wt[j][d] = bf16(W[d][j]) ----------
__global__ void k_wtrans(const float* __restrict__ W, u16* __restrict__ Wt) {
  __shared__ u16 tile[32][33];
  int bd = blockIdx.x >> 5, bj = blockIdx.x & 31;
  int tx = threadIdx.x & 31, ty = threadIdx.x >> 5;
#pragma unroll
  for (int i = 0; i < 32; i += 8)
    tile[ty + i][tx] = f2bf(W[(size_t)(bd * 32 + ty + i) * 1024 + bj * 32 + tx]);
  __syncthreads();
#pragma unroll
  for (int i = 0; i < 32; i += 8)
    Wt[(size_t)(bj * 32 + ty + i) * 1024 + bd * 32 + tx] = tile[tx][ty + i];
}

// ---------- kernel 3: zero output ----------
__global__ void k_zero(float4* __restrict__ p, int n4) {
  int idx = blockIdx.x * 256 + threadIdx.x;
  if (idx < n4) p[idx] = make_float4(0.f, 0.f, 0.f, 0.f);
}

// ---------- kernel 4: fused QKV GEMM, counted-wait double buffer ----------
__global__ __launch_bounds__(256, 2) void k_qkv(
    const u16* __restrict__ hsb, const u16* __restrict__ Wt,
    const float* __restrict__ bq, const float* __restrict__ bk, const float* __restrict__ bv,
    u16* __restrict__ Qb, u16* __restrict__ Kb, u16* __restrict__ Vt) {
  __shared__ u16 a_lds[2][128 * 64];
  __shared__ u16 b_lds[2][128 * 64];
  const int tid = threadIdx.x;
  const int lane = tid & 63, wid = tid >> 6;
  const int l15 = lane & 15, quad = lane >> 4;
  const int wr = wid >> 1, wc = wid & 1;
  const int bx = blockIdx.x & 31;
  const int by = blockIdx.x >> 5;
  const int Mbase = bx * 128;
  const int widx = by >> 3;               // 0=Q 1=K 2=V
  const int Nloc = (by & 7) * 128;

  f32x4 acc[4][4];
#pragma unroll
  for (int i = 0; i < 4; ++i)
#pragma unroll
    for (int j = 0; j < 4; ++j) acc[i][j] = (f32x4){0.f, 0.f, 0.f, 0.f};

  const u16* asrc = hsb + (size_t)Mbase * 1024;
  const u16* bsrc = Wt + (size_t)widx * 1048576 + (size_t)Nloc * 1024;

  stage256(asrc, 1024, a_lds[0], tid);
  stage256(bsrc, 1024, b_lds[0], tid);

  for (int kb = 0; kb < 16; ++kb) {
    const int cur = kb & 1;
    asm volatile("s_waitcnt vmcnt(0)" ::: "memory");
    __builtin_amdgcn_s_barrier();
    asm volatile("" ::: "memory");
    if (kb < 15) {
      stage256(asrc + (kb + 1) * 64, 1024, a_lds[cur ^ 1], tid);
      stage256(bsrc + (kb + 1) * 64, 1024, b_lds[cur ^ 1], tid);
    }
#pragma unroll
    for (int ks = 0; ks < 2; ++ks) {
      const int kc = ks * 4 + quad;
      bf16x8 af[4], bfr[4];
#pragma unroll
      for (int mt = 0; mt < 4; ++mt) af[mt] = TILE_AT(a_lds[cur], wr * 64 + mt * 16 + l15, kc);
#pragma unroll
      for (int nt = 0; nt < 4; ++nt) bfr[nt] = TILE_AT(b_lds[cur], wc * 64 + nt * 16 + l15, kc);
#pragma unroll
      for (int mt = 0; mt < 4; ++mt)
#pragma unroll
        for (int nt = 0; nt < 4; ++nt)
          acc[mt][nt] = MFMA16(af[mt], bfr[nt], acc[mt][nt]);
    }
  }
  const float* bias = (widx == 0) ? bq : ((widx == 1) ? bk : bv);
#pragma unroll
  for (int nt = 0; nt < 4; ++nt) {
    const int jloc = Nloc + wc * 64 + nt * 16 + l15;
    const float bias_v = bias[jloc];
#pragma unroll
    for (int mt = 0; mt < 4; ++mt) {
      const int Mr0 = Mbase + wr * 64 + mt * 16 + quad * 4;
      if (widx == 2) {
        const int b = Mr0 >> 11, mseq = Mr0 & 2047;
        const int g = jloc >> 7, h = jloc & 127;
        s16x4 pk;
#pragma unroll
        for (int r = 0; r < 4; ++r) pk[r] = (short)f2bf(acc[mt][nt][r] + bias_v);
        *(s16x4*)(Vt + (((size_t)b * 8 + g) * 128 + h) * 2048 + mseq) = pk;
      } else {
        u16* dst = (widx == 0) ? Qb : Kb;
#pragma unroll
        for (int r = 0; r < 4; ++r)
          dst[(size_t)(Mr0 + r) * 1024 + jloc] = f2bf(acc[mt][nt][r] + bias_v);
      }
    }
  }
}

// ---------- kernel 5: FUSED scores + softmax-over-g + PV, merged-phase ----------
// v2: QK^T(mc) and PV(mc-1) are independent (PV reads p_lds packed 2 barriers
// ago; QK^T touches only q_lds/K). They now share ONE scheduling region per
// iteration: pf/vf loads issued at even g, PV MFMAs at odd g, QK^T MFMAs every
// g. Each wave always has independent MFMA work covering the other stream's
// L2 latency (ILP substitute for the TLP that 128KB-LDS/1-block-CU denies us).
// Single p_lds buffer stays safe: PV(mc-1) reads complete before barrier 1 of
// iteration mc; pack(mc) writes between barrier 1 and 2.
// grid 256 = 64 nt x {b,msub}; XCD = bx&7 -> one (b,msub) combo per XCD.
__global__ __launch_bounds__(512, 2) void k_att(
    const u16* __restrict__ Qb, const u16* __restrict__ Kb,
    const u16* __restrict__ Vt, float* __restrict__ out) {
  __shared__ u16 q_lds[32 * 1024];    // 64 KB
  __shared__ u16 p_lds[8 * 32 * 128]; // 64 KB
  const int tid = threadIdx.x;
  const int w = tid >> 6;             // wave id; also PV's g
  const int lane = tid & 63;
  const int l15 = lane & 15, quad = lane >> 4;
  const int bx = blockIdx.x;
  const int nt = bx >> 2;
  const int bcoord = (bx >> 1) & 1;
  const int msub = bx & 1;
  const int nbase = nt * 32;
  const size_t boff = (size_t)bcoord * 2048;

  // stage Q tile 32 x 1024 (4096 16B-chunks, 8 per thread), swizzled source
#pragma unroll
  for (int i = 0; i < 8; ++i) {
    const int idx = i * 512 + tid;
    const int r = idx >> 7, pc = idx & 127;
    const int lc = pc ^ (r & 7);
    gload16(Qb + (boff + nbase + r) * 1024 + lc * 8,
            q_lds + (size_t)(i * 512 + (tid & ~63)) * 8);
  }

  f32x4 acc[2][8];
#pragma unroll
  for (int nf = 0; nf < 2; ++nf)
#pragma unroll
    for (int hf = 0; hf < 8; ++hf) acc[nf][hf] = (f32x4){0.f, 0.f, 0.f, 0.f};

  const u16* vbase = Vt + ((size_t)(bcoord * 8 + w) * 128) * 2048;
  const int lc_w = w * 2 + (quad >> 1);      // logical m-chunk of this lane's P
  const int sub = (quad & 1) * 4;            // u16 offset within chunk

  __syncthreads();

  for (int mc = 0; mc < 8; ++mc) {
    const int m0 = msub * 1024 + mc * 128;
    const int pm0 = m0 - 128;                // previous chunk (PV source)
    const u16* kp = Kb + (boff + m0 + w * 16 + l15) * 1024 + quad * 8;

    f32x4 sacc[2][8];
#pragma unroll
    for (int nf = 0; nf < 2; ++nf)
#pragma unroll
      for (int g = 0; g < 8; ++g) sacc[nf][g] = (f32x4){0.f, 0.f, 0.f, 0.f};

    bf16x8 kf[2][4];
#pragma unroll
    for (int ks = 0; ks < 4; ++ks) kf[0][ks] = *(const bf16x8*)(kp + ks * 32);
    bf16x8 vf[8], pf[2];

#pragma unroll
    for (int g = 0; g < 8; ++g) {
      if (g < 7) {
#pragma unroll
        for (int ks = 0; ks < 4; ++ks)
          kf[(g + 1) & 1][ks] = *(const bf16x8*)(kp + (g + 1) * 128 + ks * 32);
      }
      const int kblk = g >> 1;
      // issue PV operand loads for chunk mc-1 at even g (consumed at g+1)
      if (mc > 0 && (g & 1) == 0) {
#pragma unroll
        for (int nf = 0; nf < 2; ++nf) {
          const int n = nf * 16 + l15;
          pf[nf] = *(const bf16x8*)&p_lds[(size_t)((w * 32 + n) << 7) +
                                          (((kblk * 4 + quad) ^ (n & 7)) << 3)];
        }
#pragma unroll
        for (int hf = 0; hf < 8; ++hf)
          vf[hf] = *(const bf16x8*)(vbase + (size_t)(hf * 16 + l15) * 2048 +
                                    pm0 + kblk * 32 + quad * 8);
      }
      __builtin_amdgcn_s_setprio(1);
#pragma unroll
      for (int ks = 0; ks < 4; ++ks) {
        const int kc = g * 16 + ks * 4 + quad;   // logical h-chunk
#pragma unroll
        for (int nf = 0; nf < 2; ++nf) {
          const int row = nf * 16 + l15;
          bf16x8 qf = *(const bf16x8*)&q_lds[row * 1024 + ((kc ^ (row & 7)) << 3)];
          sacc[nf][g] = MFMA16(kf[g & 1][ks], qf, sacc[nf][g]);  // D[m][n]
        }
      }
      // PV MFMAs for chunk mc-1 at odd g
      if (mc > 0 && (g & 1) == 1) {
#pragma unroll
        for (int hf = 0; hf < 8; ++hf)
#pragma unroll
          for (int nf = 0; nf < 2; ++nf)
            acc[nf][hf] = MFMA16(pf[nf], vf[hf], acc[nf][hf]);
      }
      __builtin_amdgcn_s_setprio(0);
    }
    // softmax over g (register-local): lane holds n=l15(+16nf), m=w*16+quad*4+r
#pragma unroll
    for (int nf = 0; nf < 2; ++nf)
#pragma unroll
      for (int r = 0; r < 4; ++r) {
        float s[8];
#pragma unroll
        for (int g = 0; g < 8; ++g) s[g] = sacc[nf][g][r] * 0.03125f;
        float mx = s[0];
#pragma unroll
        for (int g = 1; g < 8; ++g) mx = fmaxf(mx, s[g]);
        float sum = 0.f;
#pragma unroll
        for (int g = 0; g < 8; ++g) { s[g] = __expf(s[g] - mx); sum += s[g]; }
        const float rs = 1.0f / sum;
#pragma unroll
        for (int g = 0; g < 8; ++g) sacc[nf][g][r] = s[g] * rs;
      }
    __syncthreads();   // all PV reads of chunk mc-1 done
    // pack P -> p_lds[g][n][m], 4 consecutive m per lane -> b64 writes
#pragma unroll
    for (int g = 0; g < 8; ++g)
#pragma unroll
      for (int nf = 0; nf < 2; ++nf) {
        const int n = nf * 16 + l15;
        s16x4 pk;
#pragma unroll
        for (int r = 0; r < 4; ++r) pk[r] = (short)f2bf(sacc[nf][g][r]);
        *(s16x4*)&p_lds[(size_t)((g * 32 + n) << 7) + ((lc_w ^ (n & 7)) << 3) + sub] = pk;
      }
    __syncthreads();   // chunk mc's P visible
  }
  // drain: PV for chunk 7
  {
    const int pm0 = msub * 1024 + 7 * 128;
#pragma unroll
    for (int kblk = 0; kblk < 4; ++kblk) {
      bf16x8 pf2[2];
#pragma unroll
      for (int nf = 0; nf < 2; ++nf) {
        const int n = nf * 16 + l15;
        pf2[nf] = *(const bf16x8*)&p_lds[(size_t)((w * 32 + n) << 7) +
                                         (((kblk * 4 + quad) ^ (n & 7)) << 3)];
      }
      __builtin_amdgcn_s_setprio(1);
#pragma unroll
      for (int hf = 0; hf < 8; ++hf) {
        bf16x8 vf2 = *(const bf16x8*)(vbase + (size_t)(hf * 16 + l15) * 2048 +
                                      pm0 + kblk * 32 + quad * 8);
#pragma unroll
        for (int nf = 0; nf < 2; ++nf)
          acc[nf][hf] = MFMA16(pf2[nf], vf2, acc[nf][hf]);
      }
      __builtin_amdgcn_s_setprio(0);
    }
  }
  // accumulate into out: row n = nbase + nf*16 + quad*4 + r, col = g*128 + hf*16 + l15
#pragma unroll
  for (int nf = 0; nf < 2; ++nf)
#pragma unroll
    for (int hf = 0; hf < 8; ++hf) {
      const int col = w * 128 + hf * 16 + l15;
#pragma unroll
      for (int r = 0; r < 4; ++r) {
        const int nrow = nbase + nf * 16 + quad * 4 + r;
        atomicAdd(out + (boff + nrow) * 1024 + col, acc[nf][hf][r]);
      }
    }
}

extern "C" void kernel_launch(void* const* d_in, const int* in_sizes, int n_in,
                              void* d_out, int out_size, void* d_ws, size_t ws_size,
                              hipStream_t stream) {
  const float* hs = (const float*)d_in[0];
  const float* Wq = (const float*)d_in[1];
  const float* bq = (const float*)d_in[2];
  const float* Wk = (const float*)d_in[3];
  const float* bk = (const float*)d_in[4];
  const float* Wv = (const float*)d_in[5];
  const float* bv = (const float*)d_in[6];
  float* out = (float*)d_out;

  u16* ws = (u16*)d_ws;
  u16* hsb = ws;                   // 4096x1024
  u16* Wt  = ws + 4194304;         // 3 x 1024x1024 (j-major)
  u16* Qb  = ws + 7340032;         // [b][n][1024]
  u16* Kb  = ws + 11534336;        // [b][m][1024]
  u16* Vt  = ws + 15728640;        // [b][g][h][m] = [2][8][128][2048]

  k_cast<<<2048, 256, 0, stream>>>(hs, hsb, 524288);
  k_wtrans<<<1024, 256, 0, stream>>>(Wq, Wt);
  k_wtrans<<<1024, 256, 0, stream>>>(Wk, Wt + 1048576);
  k_wtrans<<<1024, 256, 0, stream>>>(Wv, Wt + 2097152);
  k_qkv<<<32 * 24, 256, 0, stream>>>(hsb, Wt, bq, bk, bv, Qb, Kb, Vt);
  k_zero<<<4096, 256, 0, stream>>>((float4*)out, 1048576);
  k_att<<<256, 512, 0, stream>>>(Qb, Kb, Vt, out);
}